// Round 10
// baseline (609.434 us; speedup 1.0000x reference)
//
#include <hip/hip_runtime.h>
#include <math.h>

#define B_ 16
#define C_ 3
#define H_ 320
#define W_ 448
#define HW_ (H_*W_)
#define NITERS_ 5
#define LAMBDA_ 0.01f
#define HUBER_ 0.1f
#define EPS_ 1e-6f

#define BPB 64        // blocks per batch -> grid 1024 = 4 blocks/CU EXACTLY
#define CHUNK 2240    // pixels per block = 5 full image rows; 64*2240 == H*W
#define TPB 256
#define NFULL 8       // full unrolled bodies; tail body covers last 192 px

#define PARTIALS_OFF 2048

// ---------------- SE(3) exp in double ----------------
__device__ __host__ inline void se3_exp_d(const double xi[6], double T[16]) {
    double vx = xi[0], vy = xi[1], vz = xi[2];
    double wx = xi[3], wy = xi[4], wz = xi[5];
    double th2  = wx*wx + wy*wy + wz*wz;
    double th2c = th2 > 1e-16 ? th2 : 1e-16;
    double th   = sqrt(th2c);
    bool   sm   = th2 < 1e-10;
    double A  = sm ? (1.0 - th2*(1.0/6.0))   : (sin(th)/th);
    double Bc = sm ? (0.5 - th2*(1.0/24.0))  : ((1.0 - cos(th))/th2c);
    double Cc = sm ? (1.0/6.0 - th2*(1.0/120.0)) : ((1.0 - A)/th2c);
    double K[9]  = {0.0,-wz,wy,  wz,0.0,-wx,  -wy,wx,0.0};
    double K2[9];
    #pragma unroll
    for (int i = 0; i < 3; ++i)
        #pragma unroll
        for (int j = 0; j < 3; ++j) {
            double s = 0.0;
            #pragma unroll
            for (int k = 0; k < 3; ++k) s += K[i*3+k]*K[k*3+j];
            K2[i*3+j] = s;
        }
    double R[9], V[9];
    #pragma unroll
    for (int i = 0; i < 9; ++i) {
        double I = (i == 0 || i == 4 || i == 8) ? 1.0 : 0.0;
        R[i] = I + A*K[i]  + Bc*K2[i];
        V[i] = I + Bc*K[i] + Cc*K2[i];
    }
    double tx = V[0]*vx + V[1]*vy + V[2]*vz;
    double ty = V[3]*vx + V[4]*vy + V[5]*vz;
    double tz = V[6]*vx + V[7]*vy + V[8]*vz;
    T[0]=R[0]; T[1]=R[1]; T[2] =R[2]; T[3] =tx;
    T[4]=R[3]; T[5]=R[4]; T[6] =R[5]; T[7] =ty;
    T[8]=R[6]; T[9]=R[7]; T[10]=R[8]; T[11]=tz;
    T[12]=0.0; T[13]=0.0; T[14]=0.0;  T[15]=1.0;
}

// ---------------- init: T = se3_exp(pose_twist) ----------------
__global__ void init_kernel(const float* __restrict__ pose,
                            float* __restrict__ Tcur, float* __restrict__ Tinit) {
    int b = threadIdx.x;
    if (b >= B_) return;
    double xi[6];
    #pragma unroll
    for (int k = 0; k < 6; ++k) xi[k] = (double)pose[b*6+k];
    double T[16];
    se3_exp_d(xi, T);
    #pragma unroll
    for (int k = 0; k < 16; ++k) {
        float f = (float)T[k];
        Tcur[b*16+k]  = f;
        Tinit[b*16+k] = f;
    }
}

// ---------------- per-pixel GN accumulation ----------
// R4 body (fast/slow shared stencil -- best measured). Grid 1024 = whole grid
// co-resident (4 blocks/CU at VGPR<=128), one balanced round, no 4+3 split.
// NO launch_bounds min-waves (R2/R3/R6: any cap -> massive scratch spills).
// No p1v preload (-15 VGPR, keeps us under the 128 cliff at PPT 9).
__global__ __launch_bounds__(TPB)
void pixel_kernel(const float* __restrict__ I0, const float* __restrict__ I1,
                  const float* __restrict__ invD0, const float* __restrict__ invD1,
                  const float* __restrict__ intr,
                  const float* __restrict__ Tcur, const float* __restrict__ Tinit,
                  float* __restrict__ partials)
{
    // XCD-aware swizzle (bijective, 1024 % 8 == 0): 128 consecutive chunks
    // (= 2 batches) per XCD for L2 locality (R3: FETCH 193 -> 114 MB).
    const int nwg = B_*BPB;
    const int bid = blockIdx.x;
    const int swz = (bid & 7) * (nwg >> 3) + (bid >> 3);
    const int b   = swz / BPB;
    const int blk = swz % BPB;

    const float fx = intr[b*4+0], fy = intr[b*4+1];
    const float cx = intr[b*4+2], cy = intr[b*4+3];
    const float inv_fx = 1.0f/fx, inv_fy = 1.0f/fy;

    const float* Tc = Tcur  + b*16;
    const float* Ti = Tinit + b*16;
    const float Rc00=Tc[0], Rc01=Tc[1], Rc02=Tc[2],  tcx=Tc[3];
    const float Rc10=Tc[4], Rc11=Tc[5], Rc12=Tc[6],  tcy=Tc[7];
    const float Rc20=Tc[8], Rc21=Tc[9], Rc22=Tc[10], tcz=Tc[11];
    const float Ri00=Ti[0], Ri01=Ti[1], Ri02=Ti[2],  tix=Ti[3];
    const float Ri10=Ti[4], Ri11=Ti[5], Ri12=Ti[6],  tiy=Ti[7];
    const float Ri20=Ti[8], Ri21=Ti[9], Ri22=Ti[10], tiz=Ti[11];

    const float* P0 = I0    + (size_t)b*C_*HW_;
    const float* P1 = I1    + (size_t)b*C_*HW_;
    const float* D0 = invD0 + (size_t)b*HW_;
    const float* D1 = invD1 + (size_t)b*HW_;

    float acc[27];
    #pragma unroll
    for (int k = 0; k < 27; ++k) acc[k] = 0.0f;

    const int tid  = (int)threadIdx.x;
    const int base = blk*CHUNK + tid;

    // d1 preload (protects each body's serial front head). Tail slot's
    // address clamped in-chunk so no OOB; value unused when tid >= 192.
    float d1v[NFULL+1];
    #pragma unroll
    for (int i = 0; i < NFULL; ++i) d1v[i] = D1[base + i*TPB];
    {
        int p8 = base + NFULL*TPB;
        if (tid >= 192) p8 = base;          // clamp, value dead
        d1v[NFULL] = D1[p8];
    }

    auto body = [&](int p, int i5) {
        const int vcoord = p / W_;
        const int ucoord = p - vcoord*W_;

        // P1 loads issue first -- independent, overlap the stencil wait
        const float p1a = P1[p];
        const float p1b = P1[HW_ + p];
        const float p1c = P1[2*HW_ + p];

        const float iD1 = d1v[i5];
        const float iD  = fmaxf(iD1, EPS_);
        const float z1  = 1.0f / iD;
        const float x1  = ((float)ucoord - cx)*inv_fx * z1;
        const float y1  = ((float)vcoord - cy)*inv_fy * z1;

        // current warp
        const float Xc0 = Rc00*x1 + Rc01*y1 + Rc02*z1 + tcx;
        const float Xc1 = Rc10*x1 + Rc11*y1 + Rc12*z1 + tcy;
        const float Xc2 = Rc20*x1 + Rc21*y1 + Rc22*z1 + tcz;
        const float z0s = (fabsf(Xc2) > EPS_) ? Xc2 : EPS_;
        const float izc = 1.0f / z0s;
        const float u0  = fx*Xc0*izc + cx;
        const float v0  = fy*Xc1*izc + cy;
        const bool valid = (Xc2 > EPS_) && (iD1 > EPS_);
        const bool inb   = (u0 > 0.0f) && (u0 < (float)(W_-1)) &&
                           (v0 > 0.0f) && (v0 < (float)(H_-1));
        const bool vm = valid && inb;

        // initial-T projection for Jacobian (fixed linearization point)
        const float Xi0 = Ri00*x1 + Ri01*y1 + Ri02*z1 + tix;
        const float Xi1 = Ri10*x1 + Ri11*y1 + Ri12*z1 + tiy;
        const float Xi2 = Ri20*x1 + Ri21*y1 + Ri22*z1 + tiz;
        const float zis = (fabsf(Xi2) > EPS_) ? Xi2 : EPS_;
        const float izi = 1.0f / zis;
        const float aJ = fx*izi;
        const float cJ = -fx*Xi0*izi*izi;
        const float bJ = fy*izi;
        const float dJ = -fy*Xi1*izi*izi;
        const float Jw0[6] = {aJ, 0.0f, cJ, cJ*Xi1, aJ*Xi2 - cJ*Xi0, -aJ*Xi1};
        const float Jw1[6] = {0.0f, bJ, dJ, dJ*Xi1 - bJ*Xi2, -dJ*Xi0, bJ*Xi0};
        const float Jtz[6] = {0.0f, 0.0f, 1.0f, Xi1, -Xi0, 0.0f};

        // normalized grid (clipped), back to pixel coords -- mirror reference
        const float gx = fminf(fmaxf((u0/(float)(W_-1) - 0.5f)*2.0f, -2.0f), 2.0f);
        const float gy = fminf(fmaxf((v0/(float)(H_-1) - 0.5f)*2.0f, -2.0f), 2.0f);
        const float ix = (gx + 1.0f)*0.5f*(float)(W_-1);
        const float iy = (gy + 1.0f)*0.5f*(float)(H_-1);
        const float x0f = floorf(ix), y0f = floorf(iy);
        const float wx1 = ix - x0f,  wy1 = iy - y0f;
        const float wx0 = 1.0f - wx1, wy0 = 1.0f - wy1;
        const float w00 = wx0*wy0, w10 = wx1*wy0, w01 = wx0*wy1, w11 = wx1*wy1;

        float sI[3], sgxI[3], sgyI[3];
        float sD, sgxD, sgyD;

        // interior fast path: all taps AND all gradient stencil points unclamped
        const bool fast = (x0f >= 1.0f) && (x0f <= (float)(W_-3)) &&
                          (y0f >= 1.0f) && (y0f <= (float)(H_-3));

        if (__all((int)fast)) {
            const int xi0 = (int)x0f;
            const int yi0 = (int)y0f;
            const int off = yi0*W_ + xi0;
            #pragma unroll
            for (int c = 0; c < 4; ++c) {
                const float* pr = (c < 3 ? P0 + c*HW_ : D0) + off;
                // 12 unique loads covering value/dx/dy of all 4 taps
                const float am0 = pr[-1],    v00 = pr[0],     v10 = pr[1],     ap0 = pr[2];
                const float am1 = pr[W_-1],  v01 = pr[W_],    v11 = pr[W_+1],  ap1 = pr[W_+2];
                const float um0 = pr[-W_],   um1 = pr[-W_+1];
                const float dm0 = pr[2*W_],  dm1 = pr[2*W_+1];
                const float dx00 = 0.5f*(v10 - am0);
                const float dx10 = 0.5f*(ap0 - v00);
                const float dx01 = 0.5f*(v11 - am1);
                const float dx11 = 0.5f*(ap1 - v01);
                const float dy00 = 0.5f*(v01 - um0);
                const float dy10 = 0.5f*(v11 - um1);
                const float dy01 = 0.5f*(dm0 - v00);
                const float dy11 = 0.5f*(dm1 - v10);
                const float sv = w00*v00  + w10*v10  + w01*v01  + w11*v11;
                const float sx = w00*dx00 + w10*dx10 + w01*dx01 + w11*dx11;
                const float sy = w00*dy00 + w10*dy10 + w01*dy01 + w11*dy11;
                if (c < 3) { sI[c] = sv; sgxI[c] = sx; sgyI[c] = sy; }
                else       { sD    = sv; sgxD    = sx; sgyD    = sy; }
            }
        } else {
            float tI[3]  = {0,0,0}, tgx[3] = {0,0,0}, tgy[3] = {0,0,0};
            float tD = 0.0f, tgxD = 0.0f, tgyD = 0.0f;
            #pragma unroll
            for (int tap = 0; tap < 4; ++tap) {
                const float xf = x0f + (float)(tap & 1);
                const float yf = y0f + (float)(tap >> 1);
                const float wgt = ((tap & 1) ? wx1 : wx0) * ((tap >> 1) ? wy1 : wy0);
                const float m = (xf >= 0.0f && xf <= (float)(W_-1) &&
                                 yf >= 0.0f && yf <= (float)(H_-1)) ? wgt : 0.0f;
                int xc = (int)xf; xc = xc < 0 ? 0 : (xc > W_-1 ? W_-1 : xc);
                int yc = (int)yf; yc = yc < 0 ? 0 : (yc > H_-1 ? H_-1 : yc);
                const int xp = (xc+1 > W_-1) ? W_-1 : xc+1;
                const int xm = (xc-1 < 0) ? 0 : xc-1;
                const int row  = yc*W_;
                const int rowp = ((yc+1 > H_-1) ? H_-1 : yc+1)*W_;
                const int rowm = ((yc-1 < 0) ? 0 : yc-1)*W_;
                #pragma unroll
                for (int c = 0; c < 3; ++c) {
                    const float* pc = P0 + c*HW_;
                    tI[c]  += m * pc[row+xc];
                    tgx[c] += m * 0.5f*(pc[row+xp]  - pc[row+xm]);
                    tgy[c] += m * 0.5f*(pc[rowp+xc] - pc[rowm+xc]);
                }
                tD   += m * D0[row+xc];
                tgxD += m * 0.5f*(D0[row+xp]  - D0[row+xm]);
                tgyD += m * 0.5f*(D0[rowp+xc] - D0[rowm+xc]);
            }
            #pragma unroll
            for (int c = 0; c < 3; ++c) { sI[c] = tI[c]; sgxI[c] = tgx[c]; sgyI[c] = tgy[c]; }
            sD = tD; sgxD = tgxD; sgyD = tgyD;
        }

        const float p1x[3] = {p1a, p1b, p1c};

        // photometric channels
        #pragma unroll
        for (int c = 0; c < 3; ++c) {
            const float r = vm ? (p1x[c] - sI[c]) : 1e-6f;
            const float w = fminf(1.0f, HUBER_ / fmaxf(fabsf(r), EPS_));
            float J[6];
            #pragma unroll
            for (int k = 0; k < 6; ++k)
                J[k] = -(sgxI[c]*Jw0[k] + sgyI[c]*Jw1[k]);
            const float wr = w*r;
            int idx = 0;
            #pragma unroll
            for (int i2 = 0; i2 < 6; ++i2) {
                const float wJi = w*J[i2];
                #pragma unroll
                for (int j2 = i2; j2 < 6; ++j2)
                    acc[idx++] += wJi*J[j2];
                acc[21+i2] += wr*J[i2];
            }
        }
        // depth channel (scaled by LAMBDA)
        {
            const float rz = LAMBDA_ * (vm ? (izc - sD) : 1e-6f);
            const float w  = fminf(1.0f, HUBER_ / fmaxf(fabsf(rz), EPS_));
            float J[6];
            #pragma unroll
            for (int k = 0; k < 6; ++k)
                J[k] = LAMBDA_ * (Jtz[k] - (sgxD*Jw0[k] + sgyD*Jw1[k]));
            const float wr = w*rz;
            int idx = 0;
            #pragma unroll
            for (int i2 = 0; i2 < 6; ++i2) {
                const float wJi = w*J[i2];
                #pragma unroll
                for (int j2 = i2; j2 < 6; ++j2)
                    acc[idx++] += wJi*J[j2];
                acc[21+i2] += wr*J[i2];
            }
        }
    };

    #pragma unroll
    for (int i5 = 0; i5 < NFULL; ++i5)
        body(base + i5*TPB, i5);
    // tail: last 192 px of the 2240-px chunk (waves 0-2; wave 3 uniform-skips)
    if (tid < 192)
        body(base + NFULL*TPB, NFULL);

    // wave (64-lane) reduction in float
    #pragma unroll
    for (int off = 32; off >= 1; off >>= 1) {
        #pragma unroll
        for (int k = 0; k < 27; ++k)
            acc[k] += __shfl_down(acc[k], off);
    }
    __shared__ float red[TPB/64][27];
    const int lane = threadIdx.x & 63;
    const int wid  = threadIdx.x >> 6;
    if (lane == 0) {
        #pragma unroll
        for (int k = 0; k < 27; ++k) red[wid][k] = acc[k];
    }
    __syncthreads();
    if (threadIdx.x < 27) {
        float s = red[0][threadIdx.x] + red[1][threadIdx.x]
                + red[2][threadIdx.x] + red[3][threadIdx.x];
        partials[((size_t)b*BPB + blk)*27 + threadIdx.x] = s;
    }
}

// ---------------- reduce partials, solve 6x6, update T ----------------
__global__ void solve_kernel(const float* __restrict__ partials,
                             float* __restrict__ Tcur, float* __restrict__ out)
{
    const int b = blockIdx.x;
    __shared__ double S[27];
    const int t = threadIdx.x;
    if (t < 27) {
        double s = 0.0;
        const float* pp = partials + (size_t)b*BPB*27 + t;
        for (int blk = 0; blk < BPB; ++blk) s += (double)pp[blk*27];
        S[t] = s;
    }
    __syncthreads();
    if (t == 0) {
        double Hm[6][6], rhs[6];
        int idx = 0;
        for (int i = 0; i < 6; ++i)
            for (int j = i; j < 6; ++j) { Hm[i][j] = S[idx]; Hm[j][i] = S[idx]; ++idx; }
        double tr = 0.0;
        for (int i = 0; i < 6; ++i) tr += Hm[i][i];
        const double damp = tr*1e-6;
        for (int i = 0; i < 6; ++i) Hm[i][i] += damp;
        for (int i = 0; i < 6; ++i) rhs[i] = S[21+i];

        double M[6][7];
        for (int i = 0; i < 6; ++i) {
            for (int j = 0; j < 6; ++j) M[i][j] = Hm[i][j];
            M[i][6] = rhs[i];
        }
        for (int col = 0; col < 6; ++col) {
            int piv = col; double mx = fabs(M[col][col]);
            for (int r2 = col+1; r2 < 6; ++r2) {
                double a2 = fabs(M[r2][col]);
                if (a2 > mx) { mx = a2; piv = r2; }
            }
            if (piv != col)
                for (int j = col; j < 7; ++j) {
                    double tmp = M[col][j]; M[col][j] = M[piv][j]; M[piv][j] = tmp;
                }
            const double inv = 1.0 / M[col][col];
            for (int r2 = col+1; r2 < 6; ++r2) {
                const double f = M[r2][col]*inv;
                for (int j = col; j < 7; ++j) M[r2][j] -= f*M[col][j];
            }
        }
        double xi[6];
        for (int i = 5; i >= 0; --i) {
            double s2 = M[i][6];
            for (int j = i+1; j < 6; ++j) s2 -= M[i][j]*xi[j];
            xi[i] = s2 / M[i][i];
        }
        double nxi[6];
        for (int i = 0; i < 6; ++i) nxi[i] = -xi[i];
        double E[16];
        se3_exp_d(nxi, E);

        double Tc[16];
        for (int k = 0; k < 16; ++k) Tc[k] = (double)Tcur[b*16+k];
        for (int i = 0; i < 4; ++i)
            for (int j = 0; j < 4; ++j) {
                double s2 = 0.0;
                for (int k = 0; k < 4; ++k) s2 += Tc[i*4+k]*E[k*4+j];
                const float f = (float)s2;
                Tcur[b*16 + i*4 + j] = f;
                out[b*16 + i*4 + j]  = f;
            }
    }
}

extern "C" void kernel_launch(void* const* d_in, const int* in_sizes, int n_in,
                              void* d_out, int out_size, void* d_ws, size_t ws_size,
                              hipStream_t stream) {
    const float* pose  = (const float*)d_in[0];
    const float* I0    = (const float*)d_in[1];
    const float* I1    = (const float*)d_in[2];
    const float* invD0 = (const float*)d_in[3];
    const float* invD1 = (const float*)d_in[4];
    const float* intr  = (const float*)d_in[5];
    float* out = (float*)d_out;

    float* Tcur     = (float*)d_ws;
    float* Tinit    = Tcur + 256;
    float* partials = (float*)((char*)d_ws + PARTIALS_OFF);

    hipLaunchKernelGGL(init_kernel, dim3(1), dim3(64), 0, stream, pose, Tcur, Tinit);
    for (int it = 0; it < NITERS_; ++it) {
        hipLaunchKernelGGL(pixel_kernel, dim3(B_*BPB), dim3(TPB), 0, stream,
                           I0, I1, invD0, invD1, intr, Tcur, Tinit, partials);
        hipLaunchKernelGGL(solve_kernel, dim3(B_), dim3(64), 0, stream,
                           partials, Tcur, out);
    }
}

// Round 11
// 304.028 us; speedup vs baseline: 2.0045x; 2.0045x over previous
//
#include <hip/hip_runtime.h>
#include <math.h>

#define B_ 16
#define C_ 3
#define H_ 320
#define W_ 448
#define HW_ (H_*W_)
#define NITERS_ 5
#define LAMBDA_ 0.01f
#define HUBER_ 0.1f
#define EPS_ 1e-6f

#define BPB 112       // blocks per batch (1792 total) -- R4-proven shape
#define CHUNK 1280    // pixels per block == 5*TPB; 112*1280 == H*W
#define TPB 256
#define PPT 5

// workspace layout
#define PARTIALS_OFF 2048
#define PLANE_OFF    262144
#define PLANE_ELTS   ((size_t)B_*HW_)            // float4 elements
#define WS_NEED      (PLANE_OFF + PLANE_ELTS*16) // ~37 MB

// ---------------- SE(3) exp in double ----------------
__device__ __host__ inline void se3_exp_d(const double xi[6], double T[16]) {
    double vx = xi[0], vy = xi[1], vz = xi[2];
    double wx = xi[3], wy = xi[4], wz = xi[5];
    double th2  = wx*wx + wy*wy + wz*wz;
    double th2c = th2 > 1e-16 ? th2 : 1e-16;
    double th   = sqrt(th2c);
    bool   sm   = th2 < 1e-10;
    double A  = sm ? (1.0 - th2*(1.0/6.0))   : (sin(th)/th);
    double Bc = sm ? (0.5 - th2*(1.0/24.0))  : ((1.0 - cos(th))/th2c);
    double Cc = sm ? (1.0/6.0 - th2*(1.0/120.0)) : ((1.0 - A)/th2c);
    double K[9]  = {0.0,-wz,wy,  wz,0.0,-wx,  -wy,wx,0.0};
    double K2[9];
    #pragma unroll
    for (int i = 0; i < 3; ++i)
        #pragma unroll
        for (int j = 0; j < 3; ++j) {
            double s = 0.0;
            #pragma unroll
            for (int k = 0; k < 3; ++k) s += K[i*3+k]*K[k*3+j];
            K2[i*3+j] = s;
        }
    double R[9], V[9];
    #pragma unroll
    for (int i = 0; i < 9; ++i) {
        double I = (i == 0 || i == 4 || i == 8) ? 1.0 : 0.0;
        R[i] = I + A*K[i]  + Bc*K2[i];
        V[i] = I + Bc*K[i] + Cc*K2[i];
    }
    double tx = V[0]*vx + V[1]*vy + V[2]*vz;
    double ty = V[3]*vx + V[4]*vy + V[5]*vz;
    double tz = V[6]*vx + V[7]*vy + V[8]*vz;
    T[0]=R[0]; T[1]=R[1]; T[2] =R[2]; T[3] =tx;
    T[4]=R[3]; T[5]=R[4]; T[6] =R[5]; T[7] =ty;
    T[8]=R[6]; T[9]=R[7]; T[10]=R[8]; T[11]=tz;
    T[12]=0.0; T[13]=0.0; T[14]=0.0;  T[15]=1.0;
}

// ---------------- init: T = se3_exp(pose_twist) ----------------
__global__ void init_kernel(const float* __restrict__ pose,
                            float* __restrict__ Tcur, float* __restrict__ Tinit) {
    int b = threadIdx.x;
    if (b >= B_) return;
    double xi[6];
    #pragma unroll
    for (int k = 0; k < 6; ++k) xi[k] = (double)pose[b*6+k];
    double T[16];
    se3_exp_d(xi, T);
    #pragma unroll
    for (int k = 0; k < 16; ++k) {
        float f = (float)T[k];
        Tcur[b*16+k]  = f;
        Tinit[b*16+k] = f;
    }
}

// ---------------- precompute: pack (I0.rgb, invD0) into one float4 plane ----
#define PRE_BPB (HW_/TPB)   // 560
__global__ __launch_bounds__(TPB)
void pack_kernel(const float* __restrict__ I0, const float* __restrict__ invD0,
                 float4* __restrict__ P4)
{
    const int b   = blockIdx.x / PRE_BPB;
    const int rem = blockIdx.x % PRE_BPB;
    const int p   = rem*TPB + (int)threadIdx.x;
    const float* base0 = I0    + (size_t)b*C_*HW_ + p;
    const float* based = invD0 + (size_t)b*HW_   + p;
    P4[(size_t)b*HW_ + p] = make_float4(base0[0], base0[HW_], base0[2*HW_], based[0]);
}

// channel extractor (compile-time c)
__device__ __forceinline__ float chan(const float4& v, int c) {
    return (c == 0) ? v.x : (c == 1) ? v.y : (c == 2) ? v.z : v.w;
}

// ---------------- per-pixel GN accumulation (packed plane, 12 float4) ------
// 12 float4 gathers/pixel replace R4's 48 scalar gathers: ONE load batch and
// ONE latency wait per body (R4 had 4 sequential channel waits). Branchless
// R7 clamp (refcheck-proven) so unrolled bodies can overlap.
// NO launch_bounds min-waves (R2/R3/R6: any cap -> massive scratch spills).
__global__ __launch_bounds__(TPB)
void pixel_p4_kernel(const float4* __restrict__ P4,
                     const float* __restrict__ I1, const float* __restrict__ invD1,
                     const float* __restrict__ intr,
                     const float* __restrict__ Tcur, const float* __restrict__ Tinit,
                     float* __restrict__ partials)
{
    // XCD-aware swizzle (bijective, 1792 % 8 == 0): contiguous chunks per XCD.
    const int nwg = B_*BPB;
    const int bid = blockIdx.x;
    const int swz = (bid & 7) * (nwg >> 3) + (bid >> 3);
    const int b   = swz / BPB;
    const int blk = swz % BPB;

    const float fx = intr[b*4+0], fy = intr[b*4+1];
    const float cx = intr[b*4+2], cy = intr[b*4+3];
    const float inv_fx = 1.0f/fx, inv_fy = 1.0f/fy;

    const float* Tc = Tcur  + b*16;
    const float* Ti = Tinit + b*16;
    const float Rc00=Tc[0], Rc01=Tc[1], Rc02=Tc[2],  tcx=Tc[3];
    const float Rc10=Tc[4], Rc11=Tc[5], Rc12=Tc[6],  tcy=Tc[7];
    const float Rc20=Tc[8], Rc21=Tc[9], Rc22=Tc[10], tcz=Tc[11];
    const float Ri00=Ti[0], Ri01=Ti[1], Ri02=Ti[2],  tix=Ti[3];
    const float Ri10=Ti[4], Ri11=Ti[5], Ri12=Ti[6],  tiy=Ti[7];
    const float Ri20=Ti[8], Ri21=Ti[9], Ri22=Ti[10], tiz=Ti[11];

    const float4* Pb = P4 + (size_t)b*HW_;
    const float*  P1 = I1    + (size_t)b*C_*HW_;
    const float*  D1 = invD1 + (size_t)b*HW_;

    float acc[27];
    #pragma unroll
    for (int k = 0; k < 27; ++k) acc[k] = 0.0f;

    const int base = blk*CHUNK + (int)threadIdx.x;

    // d1 preload (protects each body's serial front head)
    float d1v[PPT];
    #pragma unroll
    for (int i = 0; i < PPT; ++i) d1v[i] = D1[base + i*TPB];

    auto body = [&](int i5) {
        const int p = base + i5*TPB;
        const int vcoord = p / W_;
        const int ucoord = p - vcoord*W_;

        // P1 loads issue first -- independent, overlap the stencil wait
        const float p1a = P1[p];
        const float p1b = P1[HW_ + p];
        const float p1c = P1[2*HW_ + p];

        const float iD1 = d1v[i5];
        const float iD  = fmaxf(iD1, EPS_);
        const float z1  = 1.0f / iD;
        const float x1  = ((float)ucoord - cx)*inv_fx * z1;
        const float y1  = ((float)vcoord - cy)*inv_fy * z1;

        // current warp
        const float Xc0 = Rc00*x1 + Rc01*y1 + Rc02*z1 + tcx;
        const float Xc1 = Rc10*x1 + Rc11*y1 + Rc12*z1 + tcy;
        const float Xc2 = Rc20*x1 + Rc21*y1 + Rc22*z1 + tcz;
        const float z0s = (fabsf(Xc2) > EPS_) ? Xc2 : EPS_;
        const float izc = 1.0f / z0s;
        const float u0  = fx*Xc0*izc + cx;
        const float v0  = fy*Xc1*izc + cy;
        const bool valid = (Xc2 > EPS_) && (iD1 > EPS_);
        const bool inb   = (u0 > 0.0f) && (u0 < (float)(W_-1)) &&
                           (v0 > 0.0f) && (v0 < (float)(H_-1));
        const bool vm = valid && inb;

        // initial-T projection for Jacobian (fixed linearization point)
        const float Xi0 = Ri00*x1 + Ri01*y1 + Ri02*z1 + tix;
        const float Xi1 = Ri10*x1 + Ri11*y1 + Ri12*z1 + tiy;
        const float Xi2 = Ri20*x1 + Ri21*y1 + Ri22*z1 + tiz;
        const float zis = (fabsf(Xi2) > EPS_) ? Xi2 : EPS_;
        const float izi = 1.0f / zis;
        const float aJ = fx*izi;
        const float cJ = -fx*Xi0*izi*izi;
        const float bJ = fy*izi;
        const float dJ = -fy*Xi1*izi*izi;
        const float Jw0[6] = {aJ, 0.0f, cJ, cJ*Xi1, aJ*Xi2 - cJ*Xi0, -aJ*Xi1};
        const float Jw1[6] = {0.0f, bJ, dJ, dJ*Xi1 - bJ*Xi2, -dJ*Xi0, bJ*Xi0};
        const float Jtz[6] = {0.0f, 0.0f, 1.0f, Xi1, -Xi0, 0.0f};

        // normalized grid (clipped), back to pixel coords -- mirror reference
        const float gx = fminf(fmaxf((u0/(float)(W_-1) - 0.5f)*2.0f, -2.0f), 2.0f);
        const float gy = fminf(fmaxf((v0/(float)(H_-1) - 0.5f)*2.0f, -2.0f), 2.0f);
        const float ix = (gx + 1.0f)*0.5f*(float)(W_-1);
        const float iy = (gy + 1.0f)*0.5f*(float)(H_-1);
        const float x0f = floorf(ix), y0f = floorf(iy);
        const float wx1 = ix - x0f,  wy1 = iy - y0f;
        const float wx0 = 1.0f - wx1, wy0 = 1.0f - wy1;

        // per-tap masks (reference: tap inside [0,W-1]x[0,H-1])
        const bool bx0 = (x0f >= 0.0f)  && (x0f <= (float)(W_-1));
        const bool bx1 = (x0f >= -1.0f) && (x0f <= (float)(W_-2));
        const bool by0 = (y0f >= 0.0f)  && (y0f <= (float)(H_-1));
        const bool by1 = (y0f >= -1.0f) && (y0f <= (float)(H_-2));
        const float m00 = (bx0 && by0) ? wx0*wy0 : 0.0f;
        const float m10 = (bx1 && by0) ? wx1*wy0 : 0.0f;
        const float m01 = (bx0 && by1) ? wx0*wy1 : 0.0f;
        const float m11 = (bx1 && by1) ? wx1*wy1 : 0.0f;

        // independently clamped rows/cols (R7 semantics, refcheck-proven)
        const int x0i = (int)x0f;
        const int y0i = (int)y0f;
        const int cA = min(max(x0i-1, 0), W_-1);
        const int c0 = min(max(x0i,   0), W_-1);
        const int c1 = min(max(x0i+1, 0), W_-1);
        const int cB = min(max(x0i+2, 0), W_-1);
        const int oA = min(max(y0i-1, 0), H_-1) * W_;
        const int o0 = min(max(y0i,   0), H_-1) * W_;
        const int o1 = min(max(y0i+1, 0), H_-1) * W_;
        const int oB = min(max(y0i+2, 0), H_-1) * W_;

        // single 12 x float4 gather batch: all channels, values + grad points
        const float4 fA0 = Pb[o0+cA], f00 = Pb[o0+c0], f10 = Pb[o0+c1], fB0 = Pb[o0+cB];
        const float4 fA1 = Pb[o1+cA], f01 = Pb[o1+c0], f11 = Pb[o1+c1], fB1 = Pb[o1+cB];
        const float4 up0 = Pb[oA+c0], up1 = Pb[oA+c1];
        const float4 dn0 = Pb[oB+c0], dn1 = Pb[oB+c1];

        const float p1x[3] = {p1a, p1b, p1c};

        #pragma unroll
        for (int c = 0; c < 4; ++c) {
            const float vA0 = chan(fA0,c), v00 = chan(f00,c), v10 = chan(f10,c), vB0 = chan(fB0,c);
            const float vA1 = chan(fA1,c), v01 = chan(f01,c), v11 = chan(f11,c), vB1 = chan(fB1,c);
            const float vu0 = chan(up0,c), vu1 = chan(up1,c);
            const float vd0 = chan(dn0,c), vd1 = chan(dn1,c);

            const float sv  = m00*v00 + m10*v10 + m01*v01 + m11*v11;
            const float sgx = 0.5f*(m00*(v10-vA0) + m10*(vB0-v00) +
                                    m01*(v11-vA1) + m11*(vB1-v01));
            const float sgy = 0.5f*(m00*(v01-vu0) + m10*(v11-vu1) +
                                    m01*(vd0-v00) + m11*(vd1-v10));

            float r, w;
            float J[6];
            if (c < 3) {
                r = vm ? (p1x[c] - sv) : 1e-6f;
                w = fminf(1.0f, HUBER_ / fmaxf(fabsf(r), EPS_));
                #pragma unroll
                for (int k = 0; k < 6; ++k)
                    J[k] = -(sgx*Jw0[k] + sgy*Jw1[k]);
            } else {
                r = LAMBDA_ * (vm ? (izc - sv) : 1e-6f);
                w = fminf(1.0f, HUBER_ / fmaxf(fabsf(r), EPS_));
                #pragma unroll
                for (int k = 0; k < 6; ++k)
                    J[k] = LAMBDA_ * (Jtz[k] - (sgx*Jw0[k] + sgy*Jw1[k]));
            }
            const float wr = w*r;
            int idx = 0;
            #pragma unroll
            for (int i2 = 0; i2 < 6; ++i2) {
                const float wJi = w*J[i2];
                #pragma unroll
                for (int j2 = i2; j2 < 6; ++j2)
                    acc[idx++] += wJi*J[j2];
                acc[21+i2] += wr*J[i2];
            }
        }
    };

    #pragma unroll
    for (int i5 = 0; i5 < PPT; ++i5)
        body(i5);

    // wave (64-lane) reduction in float
    #pragma unroll
    for (int off = 32; off >= 1; off >>= 1) {
        #pragma unroll
        for (int k = 0; k < 27; ++k)
            acc[k] += __shfl_down(acc[k], off);
    }
    __shared__ float red[TPB/64][27];
    const int lane = threadIdx.x & 63;
    const int wid  = threadIdx.x >> 6;
    if (lane == 0) {
        #pragma unroll
        for (int k = 0; k < 27; ++k) red[wid][k] = acc[k];
    }
    __syncthreads();
    if (threadIdx.x < 27) {
        float s = red[0][threadIdx.x] + red[1][threadIdx.x]
                + red[2][threadIdx.x] + red[3][threadIdx.x];
        partials[((size_t)b*BPB + blk)*27 + threadIdx.x] = s;
    }
}

// ---------------- legacy (R4) kernel: fallback if ws too small ----------------
__global__ __launch_bounds__(TPB)
void pixel_kernel(const float* __restrict__ I0, const float* __restrict__ I1,
                  const float* __restrict__ invD0, const float* __restrict__ invD1,
                  const float* __restrict__ intr,
                  const float* __restrict__ Tcur, const float* __restrict__ Tinit,
                  float* __restrict__ partials)
{
    const int nwg = B_*BPB;
    const int bid = blockIdx.x;
    const int swz = (bid & 7) * (nwg >> 3) + (bid >> 3);
    const int b   = swz / BPB;
    const int blk = swz % BPB;

    const float fx = intr[b*4+0], fy = intr[b*4+1];
    const float cx = intr[b*4+2], cy = intr[b*4+3];
    const float inv_fx = 1.0f/fx, inv_fy = 1.0f/fy;

    const float* Tc = Tcur  + b*16;
    const float* Ti = Tinit + b*16;
    const float Rc00=Tc[0], Rc01=Tc[1], Rc02=Tc[2],  tcx=Tc[3];
    const float Rc10=Tc[4], Rc11=Tc[5], Rc12=Tc[6],  tcy=Tc[7];
    const float Rc20=Tc[8], Rc21=Tc[9], Rc22=Tc[10], tcz=Tc[11];
    const float Ri00=Ti[0], Ri01=Ti[1], Ri02=Ti[2],  tix=Ti[3];
    const float Ri10=Ti[4], Ri11=Ti[5], Ri12=Ti[6],  tiy=Ti[7];
    const float Ri20=Ti[8], Ri21=Ti[9], Ri22=Ti[10], tiz=Ti[11];

    const float* P0 = I0    + (size_t)b*C_*HW_;
    const float* P1 = I1    + (size_t)b*C_*HW_;
    const float* D0 = invD0 + (size_t)b*HW_;
    const float* D1 = invD1 + (size_t)b*HW_;

    float acc[27];
    #pragma unroll
    for (int k = 0; k < 27; ++k) acc[k] = 0.0f;

    const int base = blk*CHUNK + (int)threadIdx.x;

    float d1v[PPT];
    float p1v[C_][PPT];
    #pragma unroll
    for (int i = 0; i < PPT; ++i) d1v[i] = D1[base + i*TPB];
    #pragma unroll
    for (int c = 0; c < C_; ++c)
        #pragma unroll
        for (int i = 0; i < PPT; ++i) p1v[c][i] = P1[c*HW_ + base + i*TPB];

    auto body = [&](int i5) {
        const int p = base + i5*TPB;
        const int vcoord = p / W_;
        const int ucoord = p - vcoord*W_;

        const float iD1 = d1v[i5];
        const float iD  = fmaxf(iD1, EPS_);
        const float z1  = 1.0f / iD;
        const float x1  = ((float)ucoord - cx)*inv_fx * z1;
        const float y1  = ((float)vcoord - cy)*inv_fy * z1;

        const float Xc0 = Rc00*x1 + Rc01*y1 + Rc02*z1 + tcx;
        const float Xc1 = Rc10*x1 + Rc11*y1 + Rc12*z1 + tcy;
        const float Xc2 = Rc20*x1 + Rc21*y1 + Rc22*z1 + tcz;
        const float z0s = (fabsf(Xc2) > EPS_) ? Xc2 : EPS_;
        const float izc = 1.0f / z0s;
        const float u0  = fx*Xc0*izc + cx;
        const float v0  = fy*Xc1*izc + cy;
        const bool valid = (Xc2 > EPS_) && (iD1 > EPS_);
        const bool inb   = (u0 > 0.0f) && (u0 < (float)(W_-1)) &&
                           (v0 > 0.0f) && (v0 < (float)(H_-1));
        const bool vm = valid && inb;

        const float Xi0 = Ri00*x1 + Ri01*y1 + Ri02*z1 + tix;
        const float Xi1 = Ri10*x1 + Ri11*y1 + Ri12*z1 + tiy;
        const float Xi2 = Ri20*x1 + Ri21*y1 + Ri22*z1 + tiz;
        const float zis = (fabsf(Xi2) > EPS_) ? Xi2 : EPS_;
        const float izi = 1.0f / zis;
        const float aJ = fx*izi;
        const float cJ = -fx*Xi0*izi*izi;
        const float bJ = fy*izi;
        const float dJ = -fy*Xi1*izi*izi;
        const float Jw0[6] = {aJ, 0.0f, cJ, cJ*Xi1, aJ*Xi2 - cJ*Xi0, -aJ*Xi1};
        const float Jw1[6] = {0.0f, bJ, dJ, dJ*Xi1 - bJ*Xi2, -dJ*Xi0, bJ*Xi0};
        const float Jtz[6] = {0.0f, 0.0f, 1.0f, Xi1, -Xi0, 0.0f};

        const float gx = fminf(fmaxf((u0/(float)(W_-1) - 0.5f)*2.0f, -2.0f), 2.0f);
        const float gy = fminf(fmaxf((v0/(float)(H_-1) - 0.5f)*2.0f, -2.0f), 2.0f);
        const float ix = (gx + 1.0f)*0.5f*(float)(W_-1);
        const float iy = (gy + 1.0f)*0.5f*(float)(H_-1);
        const float x0f = floorf(ix), y0f = floorf(iy);
        const float wx1 = ix - x0f,  wy1 = iy - y0f;
        const float wx0 = 1.0f - wx1, wy0 = 1.0f - wy1;
        const float w00 = wx0*wy0, w10 = wx1*wy0, w01 = wx0*wy1, w11 = wx1*wy1;

        float sI[3], sgxI[3], sgyI[3];
        float sD, sgxD, sgyD;

        const bool fast = (x0f >= 1.0f) && (x0f <= (float)(W_-3)) &&
                          (y0f >= 1.0f) && (y0f <= (float)(H_-3));

        if (__all((int)fast)) {
            const int xi0 = (int)x0f;
            const int yi0 = (int)y0f;
            const int off = yi0*W_ + xi0;
            #pragma unroll
            for (int c = 0; c < 4; ++c) {
                const float* pr = (c < 3 ? P0 + c*HW_ : D0) + off;
                const float am0 = pr[-1],    v00 = pr[0],     v10 = pr[1],     ap0 = pr[2];
                const float am1 = pr[W_-1],  v01 = pr[W_],    v11 = pr[W_+1],  ap1 = pr[W_+2];
                const float um0 = pr[-W_],   um1 = pr[-W_+1];
                const float dm0 = pr[2*W_],  dm1 = pr[2*W_+1];
                const float dx00 = 0.5f*(v10 - am0);
                const float dx10 = 0.5f*(ap0 - v00);
                const float dx01 = 0.5f*(v11 - am1);
                const float dx11 = 0.5f*(ap1 - v01);
                const float dy00 = 0.5f*(v01 - um0);
                const float dy10 = 0.5f*(v11 - um1);
                const float dy01 = 0.5f*(dm0 - v00);
                const float dy11 = 0.5f*(dm1 - v10);
                const float sv = w00*v00  + w10*v10  + w01*v01  + w11*v11;
                const float sx = w00*dx00 + w10*dx10 + w01*dx01 + w11*dx11;
                const float sy = w00*dy00 + w10*dy10 + w01*dy01 + w11*dy11;
                if (c < 3) { sI[c] = sv; sgxI[c] = sx; sgyI[c] = sy; }
                else       { sD    = sv; sgxD    = sx; sgyD    = sy; }
            }
        } else {
            float tI[3]  = {0,0,0}, tgx[3] = {0,0,0}, tgy[3] = {0,0,0};
            float tD = 0.0f, tgxD = 0.0f, tgyD = 0.0f;
            #pragma unroll
            for (int tap = 0; tap < 4; ++tap) {
                const float xf = x0f + (float)(tap & 1);
                const float yf = y0f + (float)(tap >> 1);
                const float wgt = ((tap & 1) ? wx1 : wx0) * ((tap >> 1) ? wy1 : wy0);
                const float m = (xf >= 0.0f && xf <= (float)(W_-1) &&
                                 yf >= 0.0f && yf <= (float)(H_-1)) ? wgt : 0.0f;
                int xc = (int)xf; xc = xc < 0 ? 0 : (xc > W_-1 ? W_-1 : xc);
                int yc = (int)yf; yc = yc < 0 ? 0 : (yc > H_-1 ? H_-1 : yc);
                const int xp = (xc+1 > W_-1) ? W_-1 : xc+1;
                const int xm = (xc-1 < 0) ? 0 : xc-1;
                const int row  = yc*W_;
                const int rowp = ((yc+1 > H_-1) ? H_-1 : yc+1)*W_;
                const int rowm = ((yc-1 < 0) ? 0 : yc-1)*W_;
                #pragma unroll
                for (int c = 0; c < 3; ++c) {
                    const float* pc = P0 + c*HW_;
                    tI[c]  += m * pc[row+xc];
                    tgx[c] += m * 0.5f*(pc[row+xp]  - pc[row+xm]);
                    tgy[c] += m * 0.5f*(pc[rowp+xc] - pc[rowm+xc]);
                }
                tD   += m * D0[row+xc];
                tgxD += m * 0.5f*(D0[row+xp]  - D0[row+xm]);
                tgyD += m * 0.5f*(D0[rowp+xc] - D0[rowm+xc]);
            }
            #pragma unroll
            for (int c = 0; c < 3; ++c) { sI[c] = tI[c]; sgxI[c] = tgx[c]; sgyI[c] = tgy[c]; }
            sD = tD; sgxD = tgxD; sgyD = tgyD;
        }

        #pragma unroll
        for (int c = 0; c < 3; ++c) {
            const float r = vm ? (p1v[c][i5] - sI[c]) : 1e-6f;
            const float w = fminf(1.0f, HUBER_ / fmaxf(fabsf(r), EPS_));
            float J[6];
            #pragma unroll
            for (int k = 0; k < 6; ++k)
                J[k] = -(sgxI[c]*Jw0[k] + sgyI[c]*Jw1[k]);
            const float wr = w*r;
            int idx = 0;
            #pragma unroll
            for (int i2 = 0; i2 < 6; ++i2) {
                const float wJi = w*J[i2];
                #pragma unroll
                for (int j2 = i2; j2 < 6; ++j2)
                    acc[idx++] += wJi*J[j2];
                acc[21+i2] += wr*J[i2];
            }
        }
        {
            const float rz = LAMBDA_ * (vm ? (izc - sD) : 1e-6f);
            const float w  = fminf(1.0f, HUBER_ / fmaxf(fabsf(rz), EPS_));
            float J[6];
            #pragma unroll
            for (int k = 0; k < 6; ++k)
                J[k] = LAMBDA_ * (Jtz[k] - (sgxD*Jw0[k] + sgyD*Jw1[k]));
            const float wr = w*rz;
            int idx = 0;
            #pragma unroll
            for (int i2 = 0; i2 < 6; ++i2) {
                const float wJi = w*J[i2];
                #pragma unroll
                for (int j2 = i2; j2 < 6; ++j2)
                    acc[idx++] += wJi*J[j2];
                acc[21+i2] += wr*J[i2];
            }
        }
    };

    #pragma unroll
    for (int i5 = 0; i5 < PPT; ++i5)
        body(i5);

    #pragma unroll
    for (int off = 32; off >= 1; off >>= 1) {
        #pragma unroll
        for (int k = 0; k < 27; ++k)
            acc[k] += __shfl_down(acc[k], off);
    }
    __shared__ float red[TPB/64][27];
    const int lane = threadIdx.x & 63;
    const int wid  = threadIdx.x >> 6;
    if (lane == 0) {
        #pragma unroll
        for (int k = 0; k < 27; ++k) red[wid][k] = acc[k];
    }
    __syncthreads();
    if (threadIdx.x < 27) {
        float s = red[0][threadIdx.x] + red[1][threadIdx.x]
                + red[2][threadIdx.x] + red[3][threadIdx.x];
        partials[((size_t)b*BPB + blk)*27 + threadIdx.x] = s;
    }
}

// ---------------- reduce partials, solve 6x6, update T ----------------
__global__ void solve_kernel(const float* __restrict__ partials,
                             float* __restrict__ Tcur, float* __restrict__ out)
{
    const int b = blockIdx.x;
    __shared__ double S[27];
    const int t = threadIdx.x;
    if (t < 27) {
        double s = 0.0;
        const float* pp = partials + (size_t)b*BPB*27 + t;
        for (int blk = 0; blk < BPB; ++blk) s += (double)pp[blk*27];
        S[t] = s;
    }
    __syncthreads();
    if (t == 0) {
        double Hm[6][6], rhs[6];
        int idx = 0;
        for (int i = 0; i < 6; ++i)
            for (int j = i; j < 6; ++j) { Hm[i][j] = S[idx]; Hm[j][i] = S[idx]; ++idx; }
        double tr = 0.0;
        for (int i = 0; i < 6; ++i) tr += Hm[i][i];
        const double damp = tr*1e-6;
        for (int i = 0; i < 6; ++i) Hm[i][i] += damp;
        for (int i = 0; i < 6; ++i) rhs[i] = S[21+i];

        double M[6][7];
        for (int i = 0; i < 6; ++i) {
            for (int j = 0; j < 6; ++j) M[i][j] = Hm[i][j];
            M[i][6] = rhs[i];
        }
        for (int col = 0; col < 6; ++col) {
            int piv = col; double mx = fabs(M[col][col]);
            for (int r2 = col+1; r2 < 6; ++r2) {
                double a2 = fabs(M[r2][col]);
                if (a2 > mx) { mx = a2; piv = r2; }
            }
            if (piv != col)
                for (int j = col; j < 7; ++j) {
                    double tmp = M[col][j]; M[col][j] = M[piv][j]; M[piv][j] = tmp;
                }
            const double inv = 1.0 / M[col][col];
            for (int r2 = col+1; r2 < 6; ++r2) {
                const double f = M[r2][col]*inv;
                for (int j = col; j < 7; ++j) M[r2][j] -= f*M[col][j];
            }
        }
        double xi[6];
        for (int i = 5; i >= 0; --i) {
            double s2 = M[i][6];
            for (int j = i+1; j < 6; ++j) s2 -= M[i][j]*xi[j];
            xi[i] = s2 / M[i][i];
        }
        double nxi[6];
        for (int i = 0; i < 6; ++i) nxi[i] = -xi[i];
        double E[16];
        se3_exp_d(nxi, E);

        double Tc[16];
        for (int k = 0; k < 16; ++k) Tc[k] = (double)Tcur[b*16+k];
        for (int i = 0; i < 4; ++i)
            for (int j = 0; j < 4; ++j) {
                double s2 = 0.0;
                for (int k = 0; k < 4; ++k) s2 += Tc[i*4+k]*E[k*4+j];
                const float f = (float)s2;
                Tcur[b*16 + i*4 + j] = f;
                out[b*16 + i*4 + j]  = f;
            }
    }
}

extern "C" void kernel_launch(void* const* d_in, const int* in_sizes, int n_in,
                              void* d_out, int out_size, void* d_ws, size_t ws_size,
                              hipStream_t stream) {
    const float* pose  = (const float*)d_in[0];
    const float* I0    = (const float*)d_in[1];
    const float* I1    = (const float*)d_in[2];
    const float* invD0 = (const float*)d_in[3];
    const float* invD1 = (const float*)d_in[4];
    const float* intr  = (const float*)d_in[5];
    float* out = (float*)d_out;

    float* Tcur     = (float*)d_ws;
    float* Tinit    = Tcur + 256;
    float* partials = (float*)((char*)d_ws + PARTIALS_OFF);

    hipLaunchKernelGGL(init_kernel, dim3(1), dim3(64), 0, stream, pose, Tcur, Tinit);

    if (ws_size >= WS_NEED) {
        float4* P4 = (float4*)((char*)d_ws + PLANE_OFF);
        hipLaunchKernelGGL(pack_kernel, dim3(B_*PRE_BPB), dim3(TPB), 0, stream,
                           I0, invD0, P4);
        for (int it = 0; it < NITERS_; ++it) {
            hipLaunchKernelGGL(pixel_p4_kernel, dim3(B_*BPB), dim3(TPB), 0, stream,
                               P4, I1, invD1, intr, Tcur, Tinit, partials);
            hipLaunchKernelGGL(solve_kernel, dim3(B_), dim3(64), 0, stream,
                               partials, Tcur, out);
        }
    } else {
        for (int it = 0; it < NITERS_; ++it) {
            hipLaunchKernelGGL(pixel_kernel, dim3(B_*BPB), dim3(TPB), 0, stream,
                               I0, I1, invD0, invD1, intr, Tcur, Tinit, partials);
            hipLaunchKernelGGL(solve_kernel, dim3(B_), dim3(64), 0, stream,
                               partials, Tcur, out);
        }
    }
}

// Round 12
// 287.225 us; speedup vs baseline: 2.1218x; 1.0585x over previous
//
#include <hip/hip_runtime.h>
#include <hip/hip_fp16.h>
#include <math.h>

#define B_ 16
#define C_ 3
#define H_ 320
#define W_ 448
#define HW_ (H_*W_)
#define NITERS_ 5
#define LAMBDA_ 0.01f
#define HUBER_ 0.1f
#define EPS_ 1e-6f

#define BPB 112       // blocks per batch (1792 total) -- proven shape
#define CHUNK 1280    // pixels per block == 5*TPB; 112*1280 == H*W
#define TPB 256
#define PPT 5

// workspace layout
#define PARTIALS_OFF 2048
#define PLANE_OFF    262144
#define PLANE_U2     ((size_t)B_*HW_*3)            // uint2 elements (24B/px)
#define WS_NEED      (PLANE_OFF + PLANE_U2*8)      // ~55.3 MB (R5 proved ws>=110MB)

// ---------------- SE(3) exp in double ----------------
__device__ __host__ inline void se3_exp_d(const double xi[6], double T[16]) {
    double vx = xi[0], vy = xi[1], vz = xi[2];
    double wx = xi[3], wy = xi[4], wz = xi[5];
    double th2  = wx*wx + wy*wy + wz*wz;
    double th2c = th2 > 1e-16 ? th2 : 1e-16;
    double th   = sqrt(th2c);
    bool   sm   = th2 < 1e-10;
    double A  = sm ? (1.0 - th2*(1.0/6.0))   : (sin(th)/th);
    double Bc = sm ? (0.5 - th2*(1.0/24.0))  : ((1.0 - cos(th))/th2c);
    double Cc = sm ? (1.0/6.0 - th2*(1.0/120.0)) : ((1.0 - A)/th2c);
    double K[9]  = {0.0,-wz,wy,  wz,0.0,-wx,  -wy,wx,0.0};
    double K2[9];
    #pragma unroll
    for (int i = 0; i < 3; ++i)
        #pragma unroll
        for (int j = 0; j < 3; ++j) {
            double s = 0.0;
            #pragma unroll
            for (int k = 0; k < 3; ++k) s += K[i*3+k]*K[k*3+j];
            K2[i*3+j] = s;
        }
    double R[9], V[9];
    #pragma unroll
    for (int i = 0; i < 9; ++i) {
        double I = (i == 0 || i == 4 || i == 8) ? 1.0 : 0.0;
        R[i] = I + A*K[i]  + Bc*K2[i];
        V[i] = I + Bc*K[i] + Cc*K2[i];
    }
    double tx = V[0]*vx + V[1]*vy + V[2]*vz;
    double ty = V[3]*vx + V[4]*vy + V[5]*vz;
    double tz = V[6]*vx + V[7]*vy + V[8]*vz;
    T[0]=R[0]; T[1]=R[1]; T[2] =R[2]; T[3] =tx;
    T[4]=R[3]; T[5]=R[4]; T[6] =R[5]; T[7] =ty;
    T[8]=R[6]; T[9]=R[7]; T[10]=R[8]; T[11]=tz;
    T[12]=0.0; T[13]=0.0; T[14]=0.0;  T[15]=1.0;
}

// ---------------- init: T = se3_exp(pose_twist) ----------------
__global__ void init_kernel(const float* __restrict__ pose,
                            float* __restrict__ Tcur, float* __restrict__ Tinit) {
    int b = threadIdx.x;
    if (b >= B_) return;
    double xi[6];
    #pragma unroll
    for (int k = 0; k < 6; ++k) xi[k] = (double)pose[b*6+k];
    double T[16];
    se3_exp_d(xi, T);
    #pragma unroll
    for (int k = 0; k < 16; ++k) {
        float f = (float)T[k];
        Tcur[b*16+k]  = f;
        Tinit[b*16+k] = f;
    }
}

// ---------------- precompute: fp16 12-ch plane {v,dx,dy} x {r,g,b,invD0} ----
#define PRE_BPB (HW_/TPB)   // 560
__device__ __forceinline__ unsigned pk16(float a, float b) {
    __half2 h = __floats2half2_rn(a, b);
    unsigned u; __builtin_memcpy(&u, &h, 4); return u;
}
__global__ __launch_bounds__(TPB)
void pack_kernel(const float* __restrict__ I0, const float* __restrict__ invD0,
                 uint2* __restrict__ P2)
{
    const int b   = blockIdx.x / PRE_BPB;
    const int rem = blockIdx.x % PRE_BPB;
    const int p   = rem*TPB + (int)threadIdx.x;
    const int y   = p / W_;
    const int x   = p - y*W_;
    const int xp  = (x < W_-1) ? 1 : 0;
    const int xm  = (x > 0) ? -1 : 0;
    const int yp  = (y < H_-1) ? W_ : 0;
    const int ym  = (y > 0) ? -W_ : 0;

    const float* s0 = I0    + (size_t)b*C_*HW_ + p;
    const float* sd = invD0 + (size_t)b*HW_   + p;

    const float v0 = s0[0], v1 = s0[HW_], v2 = s0[2*HW_], v3 = sd[0];
    const float dx0 = 0.5f*(s0[xp]       - s0[xm]);
    const float dx1 = 0.5f*(s0[HW_+xp]   - s0[HW_+xm]);
    const float dx2 = 0.5f*(s0[2*HW_+xp] - s0[2*HW_+xm]);
    const float dx3 = 0.5f*(sd[xp]       - sd[xm]);
    const float dy0 = 0.5f*(s0[yp]       - s0[ym]);
    const float dy1 = 0.5f*(s0[HW_+yp]   - s0[HW_+ym]);
    const float dy2 = 0.5f*(s0[2*HW_+yp] - s0[2*HW_+ym]);
    const float dy3 = 0.5f*(sd[yp]       - sd[ym]);

    const size_t o = ((size_t)b*HW_ + p)*3;
    P2[o+0] = make_uint2(pk16(v0,v1),  pk16(v2,v3));
    P2[o+1] = make_uint2(pk16(dx0,dx1),pk16(dx2,dx3));
    P2[o+2] = make_uint2(pk16(dy0,dy1),pk16(dy2,dy3));
}

__device__ __forceinline__ float2 unp(unsigned u) {
    __half2 h; __builtin_memcpy(&h, &u, 4);
    return __half22float2(h);
}

// ---------------- per-pixel GN accumulation (fp16 plane + Jt-factorized) ----
// 4 taps x 24B fp16 (values+gradients precomputed -> exact reference
// grad-plane-then-bilinear semantics, R5/R9-proven). Accumulate factorized:
// all J rows = (h 1x3)*Jt, Jt=[I|-skew(X)] -> per-pixel 3x3 Gram S + u,
// expanded once via M=[[S,-SK],[.,K'SK]], rhs=[u;Xxu].
// NO launch_bounds min-waves (R2/R3/R6 spill history).
__global__ __launch_bounds__(TPB)
void pixel_h16_kernel(const uint2* __restrict__ P2,
                      const float* __restrict__ I1, const float* __restrict__ invD1,
                      const float* __restrict__ intr,
                      const float* __restrict__ Tcur, const float* __restrict__ Tinit,
                      float* __restrict__ partials)
{
    // XCD-aware swizzle (bijective, 1792 % 8 == 0): contiguous chunks per XCD.
    const int nwg = B_*BPB;
    const int bid = blockIdx.x;
    const int swz = (bid & 7) * (nwg >> 3) + (bid >> 3);
    const int b   = swz / BPB;
    const int blk = swz % BPB;

    const float fx = intr[b*4+0], fy = intr[b*4+1];
    const float cx = intr[b*4+2], cy = intr[b*4+3];
    const float inv_fx = 1.0f/fx, inv_fy = 1.0f/fy;

    const float* Tc = Tcur  + b*16;
    const float* Ti = Tinit + b*16;
    const float Rc00=Tc[0], Rc01=Tc[1], Rc02=Tc[2],  tcx=Tc[3];
    const float Rc10=Tc[4], Rc11=Tc[5], Rc12=Tc[6],  tcy=Tc[7];
    const float Rc20=Tc[8], Rc21=Tc[9], Rc22=Tc[10], tcz=Tc[11];
    const float Ri00=Ti[0], Ri01=Ti[1], Ri02=Ti[2],  tix=Ti[3];
    const float Ri10=Ti[4], Ri11=Ti[5], Ri12=Ti[6],  tiy=Ti[7];
    const float Ri20=Ti[8], Ri21=Ti[9], Ri22=Ti[10], tiz=Ti[11];

    const uint2* Pb = P2 + (size_t)b*HW_*3;
    const float* P1 = I1    + (size_t)b*C_*HW_;
    const float* D1 = invD1 + (size_t)b*HW_;

    float acc[27];
    #pragma unroll
    for (int k = 0; k < 27; ++k) acc[k] = 0.0f;

    const int base = blk*CHUNK + (int)threadIdx.x;

    // d1 preload (protects each body's serial front head)
    float d1v[PPT];
    #pragma unroll
    for (int i = 0; i < PPT; ++i) d1v[i] = D1[base + i*TPB];

    auto body = [&](int i5) {
        const int p = base + i5*TPB;
        const int vcoord = p / W_;
        const int ucoord = p - vcoord*W_;

        // P1 loads issue first -- independent, overlap the gather wait
        const float p1a = P1[p];
        const float p1b = P1[HW_ + p];
        const float p1c = P1[2*HW_ + p];

        const float iD1 = d1v[i5];
        const float iD  = fmaxf(iD1, EPS_);
        const float z1  = 1.0f / iD;
        const float x1  = ((float)ucoord - cx)*inv_fx * z1;
        const float y1  = ((float)vcoord - cy)*inv_fy * z1;

        // current warp
        const float Xc0 = Rc00*x1 + Rc01*y1 + Rc02*z1 + tcx;
        const float Xc1 = Rc10*x1 + Rc11*y1 + Rc12*z1 + tcy;
        const float Xc2 = Rc20*x1 + Rc21*y1 + Rc22*z1 + tcz;
        const float z0s = (fabsf(Xc2) > EPS_) ? Xc2 : EPS_;
        const float izc = 1.0f / z0s;
        const float u0  = fx*Xc0*izc + cx;
        const float v0  = fy*Xc1*izc + cy;
        const bool valid = (Xc2 > EPS_) && (iD1 > EPS_);
        const bool inb   = (u0 > 0.0f) && (u0 < (float)(W_-1)) &&
                           (v0 > 0.0f) && (v0 < (float)(H_-1));
        const bool vm = valid && inb;

        // initial-T projection for Jacobian (fixed linearization point)
        const float Xi0 = Ri00*x1 + Ri01*y1 + Ri02*z1 + tix;
        const float Xi1 = Ri10*x1 + Ri11*y1 + Ri12*z1 + tiy;
        const float Xi2 = Ri20*x1 + Ri21*y1 + Ri22*z1 + tiz;
        const float zis = (fabsf(Xi2) > EPS_) ? Xi2 : EPS_;
        const float izi = 1.0f / zis;
        const float aJ = fx*izi;
        const float cJ = -fx*Xi0*izi*izi;
        const float bJ = fy*izi;
        const float dJ = -fy*Xi1*izi*izi;

        // normalized grid (clipped), back to pixel coords -- mirror reference
        const float gx = fminf(fmaxf((u0/(float)(W_-1) - 0.5f)*2.0f, -2.0f), 2.0f);
        const float gy = fminf(fmaxf((v0/(float)(H_-1) - 0.5f)*2.0f, -2.0f), 2.0f);
        const float ix = (gx + 1.0f)*0.5f*(float)(W_-1);
        const float iy = (gy + 1.0f)*0.5f*(float)(H_-1);
        const float x0f = floorf(ix), y0f = floorf(iy);
        const float wx1 = ix - x0f,  wy1 = iy - y0f;
        const float wx0 = 1.0f - wx1, wy0 = 1.0f - wy1;

        // per-tap masks (reference: tap inside [0,W-1]x[0,H-1])
        const bool bx0 = (x0f >= 0.0f)  && (x0f <= (float)(W_-1));
        const bool bx1 = (x0f >= -1.0f) && (x0f <= (float)(W_-2));
        const bool by0 = (y0f >= 0.0f)  && (y0f <= (float)(H_-1));
        const bool by1 = (y0f >= -1.0f) && (y0f <= (float)(H_-2));
        const float m00 = (bx0 && by0) ? wx0*wy0 : 0.0f;
        const float m10 = (bx1 && by0) ? wx1*wy0 : 0.0f;
        const float m01 = (bx0 && by1) ? wx0*wy1 : 0.0f;
        const float m11 = (bx1 && by1) ? wx1*wy1 : 0.0f;

        const int x0i = (int)x0f;
        const int y0i = (int)y0f;
        const int c0 = min(max(x0i,   0), W_-1);
        const int c1 = min(max(x0i+1, 0), W_-1);
        const int o0 = min(max(y0i,   0), H_-1) * W_;
        const int o1 = min(max(y0i+1, 0), H_-1) * W_;

        // single gather batch: 4 taps x (16B + 8B)
        const int q00 = (o0+c0)*3, q10 = (o0+c1)*3, q01 = (o1+c0)*3, q11 = (o1+c1)*3;
        uint4 A00, A10, A01, A11;       // v.rgbd + dx.rgbd
        uint2 C00, C10, C01, C11;       // dy.rgbd
        __builtin_memcpy(&A00, &Pb[q00], 16); C00 = Pb[q00+2];
        __builtin_memcpy(&A10, &Pb[q10], 16); C10 = Pb[q10+2];
        __builtin_memcpy(&A01, &Pb[q01], 16); C01 = Pb[q01+2];
        __builtin_memcpy(&A11, &Pb[q11], 16); C11 = Pb[q11+2];

        float sv0=0,sv1=0,sv2=0,sv3=0;
        float gx0=0,gx1=0,gx2=0,gx3=0;
        float gy0=0,gy1=0,gy2=0,gy3=0;
        #define BLEND(Av, Cv, m) { float2 t;                          \
            t = unp(Av.x); sv0 += m*t.x; sv1 += m*t.y;                \
            t = unp(Av.y); sv2 += m*t.x; sv3 += m*t.y;                \
            t = unp(Av.z); gx0 += m*t.x; gx1 += m*t.y;                \
            t = unp(Av.w); gx2 += m*t.x; gx3 += m*t.y;                \
            t = unp(Cv.x); gy0 += m*t.x; gy1 += m*t.y;                \
            t = unp(Cv.y); gy2 += m*t.x; gy3 += m*t.y; }
        BLEND(A00, C00, m00)
        BLEND(A10, C10, m10)
        BLEND(A01, C01, m01)
        BLEND(A11, C11, m11)
        #undef BLEND

        // ---- factorized accumulate: S (3x3 sym) and u over 4 channels ----
        float S00=0,S01=0,S02=0,S11=0,S12=0,S22=0, U0=0,U1=0,U2=0;
        #define PHOTO(SVc, GXc, GYc, P1c) {                            \
            const float r  = vm ? (P1c - SVc) : 1e-6f;                 \
            const float w  = fminf(1.0f, HUBER_ / fmaxf(fabsf(r), EPS_)); \
            const float hx = GXc*aJ, hy = GYc*bJ, hz = GXc*cJ + GYc*dJ;  \
            const float whx = w*hx, why = w*hy, wr = w*r;              \
            S00 += whx*hx; S01 += whx*hy; S02 += whx*hz;               \
            S11 += why*hy; S12 += why*hz; S22 += w*hz*hz;              \
            U0 -= wr*hx; U1 -= wr*hy; U2 -= wr*hz; }
        PHOTO(sv0, gx0, gy0, p1a)
        PHOTO(sv1, gx1, gy1, p1b)
        PHOTO(sv2, gx2, gy2, p1c)
        #undef PHOTO
        {   // depth channel: J = LAMBDA*(e3 - h_d)*Jt
            const float rz = LAMBDA_*(vm ? (izc - sv3) : 1e-6f);
            const float w  = fminf(1.0f, HUBER_ / fmaxf(fabsf(rz), EPS_));
            const float hx = gx3*aJ, hy = gy3*bJ, hz = gx3*cJ + gy3*dJ;
            const float qx = -hx, qy = -hy, qz = 1.0f - hz;
            const float wl2 = w*(LAMBDA_*LAMBDA_);
            const float wqx = wl2*qx, wqy = wl2*qy;
            S00 += wqx*qx; S01 += wqx*qy; S02 += wqx*qz;
            S11 += wqy*qy; S12 += wqy*qz; S22 += wl2*qz*qz;
            const float wrl = w*rz*LAMBDA_;
            U0 += wrl*qx; U1 += wrl*qy; U2 += wrl*qz;
        }
        // expand via Jt = [I | -K], K = skew(Xi): M=[[S,-SK],[.,K'SK]]
        const float x = Xi0, y = Xi1, z = Xi2;
        const float P00 =  S01*z - S02*y, P01 = -S00*z + S02*x, P02 =  S00*y - S01*x;
        const float P10 =  S11*z - S12*y, P11 = -S01*z + S12*x, P12 =  S01*y - S11*x;
        const float P20 =  S12*z - S22*y, P21 = -S02*z + S22*x, P22 =  S02*y - S12*x;
        const float Q00 =  z*P10 - y*P20, Q01 =  z*P11 - y*P21, Q02 =  z*P12 - y*P22;
        const float Q11 = -z*P01 + x*P21, Q12 = -z*P02 + x*P22;
        const float Q22 =  y*P02 - x*P12;
        acc[0]  += S00; acc[1]  += S01; acc[2]  += S02;
        acc[3]  += S11; acc[4]  += S12; acc[5]  += S22;
        acc[6]  -= P00; acc[7]  -= P01; acc[8]  -= P02;
        acc[9]  -= P10; acc[10] -= P11; acc[11] -= P12;
        acc[12] -= P20; acc[13] -= P21; acc[14] -= P22;
        acc[15] += Q00; acc[16] += Q01; acc[17] += Q02;
        acc[18] += Q11; acc[19] += Q12; acc[20] += Q22;
        acc[21] += U0; acc[22] += U1; acc[23] += U2;
        acc[24] += y*U2 - z*U1;
        acc[25] += z*U0 - x*U2;
        acc[26] += x*U1 - y*U0;
    };

    #pragma unroll
    for (int i5 = 0; i5 < PPT; ++i5)
        body(i5);

    // wave (64-lane) reduction in float
    #pragma unroll
    for (int off = 32; off >= 1; off >>= 1) {
        #pragma unroll
        for (int k = 0; k < 27; ++k)
            acc[k] += __shfl_down(acc[k], off);
    }
    __shared__ float red[TPB/64][27];
    const int lane = threadIdx.x & 63;
    const int wid  = threadIdx.x >> 6;
    if (lane == 0) {
        #pragma unroll
        for (int k = 0; k < 27; ++k) red[wid][k] = acc[k];
    }
    __syncthreads();
    if (threadIdx.x < 27) {
        float s = red[0][threadIdx.x] + red[1][threadIdx.x]
                + red[2][threadIdx.x] + red[3][threadIdx.x];
        partials[((size_t)b*BPB + blk)*27 + threadIdx.x] = s;
    }
}

// ---------------- reduce partials, solve 6x6, update T ----------------
// partials layout: 0-5 S upper; 6-14 topright 3x3 row-major; 15-20 BR upper;
// 21-26 rhs.
__global__ void solve_kernel(const float* __restrict__ partials,
                             float* __restrict__ Tcur, float* __restrict__ out)
{
    const int b = blockIdx.x;
    __shared__ double S[27];
    const int t = threadIdx.x;
    if (t < 27) {
        double s = 0.0;
        const float* pp = partials + (size_t)b*BPB*27 + t;
        for (int blk = 0; blk < BPB; ++blk) s += (double)pp[blk*27];
        S[t] = s;
    }
    __syncthreads();
    if (t == 0) {
        double Hm[6][6], rhs[6];
        Hm[0][0]=S[0];  Hm[0][1]=S[1];  Hm[0][2]=S[2];
        Hm[1][1]=S[3];  Hm[1][2]=S[4];  Hm[2][2]=S[5];
        for (int i = 0; i < 3; ++i)
            for (int j = 0; j < 3; ++j)
                Hm[i][3+j] = S[6 + i*3 + j];
        Hm[3][3]=S[15]; Hm[3][4]=S[16]; Hm[3][5]=S[17];
        Hm[4][4]=S[18]; Hm[4][5]=S[19]; Hm[5][5]=S[20];
        for (int i = 0; i < 6; ++i)
            for (int j = 0; j < i; ++j) Hm[i][j] = Hm[j][i];
        for (int i = 0; i < 6; ++i) rhs[i] = S[21+i];

        double tr = 0.0;
        for (int i = 0; i < 6; ++i) tr += Hm[i][i];
        const double damp = tr*1e-6;
        for (int i = 0; i < 6; ++i) Hm[i][i] += damp;

        double M[6][7];
        for (int i = 0; i < 6; ++i) {
            for (int j = 0; j < 6; ++j) M[i][j] = Hm[i][j];
            M[i][6] = rhs[i];
        }
        for (int col = 0; col < 6; ++col) {
            int piv = col; double mx = fabs(M[col][col]);
            for (int r2 = col+1; r2 < 6; ++r2) {
                double a2 = fabs(M[r2][col]);
                if (a2 > mx) { mx = a2; piv = r2; }
            }
            if (piv != col)
                for (int j = col; j < 7; ++j) {
                    double tmp = M[col][j]; M[col][j] = M[piv][j]; M[piv][j] = tmp;
                }
            const double inv = 1.0 / M[col][col];
            for (int r2 = col+1; r2 < 6; ++r2) {
                const double f = M[r2][col]*inv;
                for (int j = col; j < 7; ++j) M[r2][j] -= f*M[col][j];
            }
        }
        double xi[6];
        for (int i = 5; i >= 0; --i) {
            double s2 = M[i][6];
            for (int j = i+1; j < 6; ++j) s2 -= M[i][j]*xi[j];
            xi[i] = s2 / M[i][i];
        }
        double nxi[6];
        for (int i = 0; i < 6; ++i) nxi[i] = -xi[i];
        double E[16];
        se3_exp_d(nxi, E);

        double Tc[16];
        for (int k = 0; k < 16; ++k) Tc[k] = (double)Tcur[b*16+k];
        for (int i = 0; i < 4; ++i)
            for (int j = 0; j < 4; ++j) {
                double s2 = 0.0;
                for (int k = 0; k < 4; ++k) s2 += Tc[i*4+k]*E[k*4+j];
                const float f = (float)s2;
                Tcur[b*16 + i*4 + j] = f;
                out[b*16 + i*4 + j]  = f;
            }
    }
}

extern "C" void kernel_launch(void* const* d_in, const int* in_sizes, int n_in,
                              void* d_out, int out_size, void* d_ws, size_t ws_size,
                              hipStream_t stream) {
    const float* pose  = (const float*)d_in[0];
    const float* I0    = (const float*)d_in[1];
    const float* I1    = (const float*)d_in[2];
    const float* invD0 = (const float*)d_in[3];
    const float* invD1 = (const float*)d_in[4];
    const float* intr  = (const float*)d_in[5];
    float* out = (float*)d_out;

    float* Tcur     = (float*)d_ws;
    float* Tinit    = Tcur + 256;
    float* partials = (float*)((char*)d_ws + PARTIALS_OFF);
    uint2* P2       = (uint2*)((char*)d_ws + PLANE_OFF);
    // ws_size >= 110 MB established empirically (R5/R9 planes path ran);
    // WS_NEED here is only ~55 MB.

    hipLaunchKernelGGL(init_kernel, dim3(1), dim3(64), 0, stream, pose, Tcur, Tinit);
    hipLaunchKernelGGL(pack_kernel, dim3(B_*PRE_BPB), dim3(TPB), 0, stream,
                       I0, invD0, P2);
    for (int it = 0; it < NITERS_; ++it) {
        hipLaunchKernelGGL(pixel_h16_kernel, dim3(B_*BPB), dim3(TPB), 0, stream,
                           P2, I1, invD1, intr, Tcur, Tinit, partials);
        hipLaunchKernelGGL(solve_kernel, dim3(B_), dim3(64), 0, stream,
                           partials, Tcur, out);
    }
}